// Round 1
// baseline (73.664 us; speedup 1.0000x reference)
//
#include <hip/hip_runtime.h>

#define SIDE 128
#define PI_F 3.14159265358979f

// out[b,0,i,j] = sum_{a,f} coef[a,f] * exp(-c[a,f]*((j-64-x_ba)^2 + (i-64-y_ba)^2))
//   invb = 4*pi/ff_b ; coef = ff_a*invb ; c = pi*invb >= 2*pi^2 ~= 19.7 (ff_b<=2)
// => each (a,f) Gaussian is ultra-narrow (sigma ~0.16px). Scatter only the
// window where the term exceeds ~1e-14 absolute (threshold is 3.48).
__global__ void potential_scatter(const float* __restrict__ coords,
                                  const float* __restrict__ ff_a,
                                  const float* __restrict__ ff_b,
                                  float* __restrict__ out,
                                  int B, int A) {
    int tid = blockIdx.x * blockDim.x + threadIdx.x;
    int total = B * A * 5;
    if (tid >= total) return;
    int f  = tid % 5;
    int ba = tid / 5;
    int a  = ba % A;
    int b  = ba / A;

    float x  = coords[(size_t)(b * A + a) * 3 + 0];
    float y  = coords[(size_t)(b * A + a) * 3 + 1];
    float fa = ff_a[a * 5 + f];
    float fb = ff_b[a * 5 + f];

    float invb = (4.0f * PI_F) / fb;
    float coef = fa * invb;          // peak amplitude, in [~3.1, ~50]
    float c    = PI_F * invb;        // exponent scale, in [~19.7, ~79]

    // pixel-space center: dx = j - cx, dy = i - cy
    float cx = x + 64.0f;
    float cy = y + 64.0f;

    // include pixels with coef*exp(-c*d2) > ~1e-14  <=>  c*d2 < ln(coef)+32
    float r2 = (__logf(coef) + 32.0f) / c;
    float r  = sqrtf(r2);

    int j0 = max(0, (int)ceilf(cx - r));
    int j1 = min(SIDE - 1, (int)floorf(cx + r));
    int i0 = max(0, (int)ceilf(cy - r));
    int i1 = min(SIDE - 1, (int)floorf(cy + r));
    if (j1 < j0 || i1 < i0) return;  // atom's blob entirely off-grid

    float* outb = out + (size_t)b * (SIDE * SIDE);
    for (int i = i0; i <= i1; ++i) {
        float dy = (float)i - cy;
        float wy = coef * __expf(-c * dy * dy);
        for (int j = j0; j <= j1; ++j) {
            float dx = (float)j - cx;
            float v  = wy * __expf(-c * dx * dx);
            atomicAdd(&outb[i * SIDE + j], v);
        }
    }
}

extern "C" void kernel_launch(void* const* d_in, const int* in_sizes, int n_in,
                              void* d_out, int out_size, void* d_ws, size_t ws_size,
                              hipStream_t stream) {
    const float* coords = (const float*)d_in[0];
    const float* ffa    = (const float*)d_in[1];
    const float* ffb    = (const float*)d_in[2];
    float* out = (float*)d_out;

    int A = in_sizes[1] / 5;          // 2048
    int B = in_sizes[0] / (A * 3);    // 4

    // d_out is poisoned 0xAA before every launch; zero it (capture-legal).
    hipMemsetAsync(d_out, 0, (size_t)out_size * sizeof(float), stream);

    int total = B * A * 5;            // 40960 threads
    int block = 256;
    int grid  = (total + block - 1) / block;
    potential_scatter<<<grid, block, 0, stream>>>(coords, ffa, ffb, out, B, A);
}